// Round 10
// baseline (93.415 us; speedup 1.0000x reference)
//
#include <hip/hip_runtime.h>

typedef float f32x4 __attribute__((ext_vector_type(4)));
typedef short s16x4 __attribute__((ext_vector_type(4)));
typedef float f32x16 __attribute__((ext_vector_type(16)));

#define M_DIM 32
#define N_DIM 8192
#define K_DIM 8192
#define NBLK (K_DIM / 16)   // 512 fp4 blocks along K
#define KSPLIT 8
#define SSTEPS 8            // 32-k supersteps per wave (256 k)
#define SCL_LD 66           // padded LDS stride (8-B aligned, low conflict)

// float -> bf16 bits, round-to-nearest-even (data has no NaNs)
__device__ inline unsigned short f2bf(float f) {
    unsigned int u = __float_as_uint(f);
    u = (u + 0x7FFFu + ((u >> 16) & 1u)) >> 16;
    return (unsigned short)u;
}

// Nearest FP4 (e2m1); ties at the boundary go DOWN (searchsorted side='left').
__device__ inline float round_fp4(float x) {
    float a = fabsf(x);
    float g;
    if (a > 2.5f)        g = (a > 5.0f) ? 6.0f : ((a > 3.5f) ? 4.0f : 3.0f);
    else if (a > 1.25f)  g = (a > 1.75f) ? 2.0f : 1.5f;
    else                 g = (a > 0.75f) ? 1.0f : ((a > 0.25f) ? 0.5f : 0.0f);
    return copysignf(g, x);
}

// Saturating RNE cast to float8_e4m3fn and back (v >= 0 here).
__device__ inline float cast_e4m3(float v) {
    v = fminf(v, 448.0f);
    if (v < 0.015625f) {                       // subnormal range, step 2^-9
        return rintf(v * 512.0f) * (1.0f / 512.0f);
    }
    int e; float m = frexpf(v, &e);            // m in [0.5, 1)
    return ldexpf(rintf(m * 16.0f) * 0.0625f, e);
}

// ---------------------------------------------------------------------------
// Fused prep: blocks 0..63  -> NVFP4 fake-quant of x into xpack (32x32 B-frag
//             layout), blocks 64..319 -> out[m][n] = bias[n]
// xpack short index: (ss*4 + t*2 + h)*256 + m*8 + j  holds
//   x_dq[m][k = ss*32 + t*16 + h*8 + j]
// (B-frag for mfma_32x32x16: lane l reads col=l&31, k-half h=l>>5, 8 shorts)
// ---------------------------------------------------------------------------
__global__ void prep_kernel(const float* __restrict__ x,
                            const float* __restrict__ input_scale,
                            const float* __restrict__ bias,
                            unsigned short* __restrict__ xpack,
                            float* __restrict__ out) {
    if (blockIdx.x >= 64) {
        int i = (blockIdx.x - 64) * blockDim.x + threadIdx.x;  // 65536 thr * 4 f
        f32x4 b = *(const f32x4*)(bias + ((i * 4) & (N_DIM - 1)));
        *(f32x4*)(out + (size_t)i * 4) = b;
        return;
    }
    int tid = blockIdx.x * blockDim.x + threadIdx.x;   // 16384 threads
    int m = tid >> 9;          // row 0..31
    int b = tid & 511;         // 16-block along K
    const float is = input_scale[0];

    const float* xp = x + (size_t)m * K_DIM + b * 16;
    f32x4 l0 = *(const f32x4*)(xp);
    f32x4 l1 = *(const f32x4*)(xp + 4);
    f32x4 l2 = *(const f32x4*)(xp + 8);
    f32x4 l3 = *(const f32x4*)(xp + 12);
    float v[16];
    #pragma unroll
    for (int i = 0; i < 4; ++i) { v[i]=l0[i]; v[4+i]=l1[i]; v[8+i]=l2[i]; v[12+i]=l3[i]; }

    float amax = 0.f;
    #pragma unroll
    for (int i = 0; i < 16; ++i) amax = fmaxf(amax, fabsf(v[i]));

    float sf = cast_e4m3(amax / 6.0f / is);
    float scale = sf * is;

    int ss = b >> 1;           // 32-k superstep
    int t  = b & 1;            // 16-k half within superstep
    unsigned short* base = xpack + ((size_t)ss * 4 + t * 2) * 256 + m * 8;
    #pragma unroll
    for (int h = 0; h < 2; ++h) {
        unsigned short tmp[8];
        #pragma unroll
        for (int j = 0; j < 8; ++j) {
            float q = 0.f;
            int i = h * 8 + j;
            if (scale > 0.f) q = round_fp4(v[i] / scale) * scale;
            tmp[j] = f2bf(q);
        }
        *(s16x4*)(base + h * 256)     = *(s16x4*)(tmp);
        *(s16x4*)(base + h * 256 + 4) = *(s16x4*)(tmp + 4);
    }
}

// ---------------------------------------------------------------------------
// Phase 2: streaming split-K GEMM on mfma_f32_32x32x16_bf16.
// Grid 2048 x 256 thr (4 waves) -> 8 blocks/CU, 32 waves/CU.
// Wave tile: 32 n-rows x 32 m x 256 k (8 supersteps of 32 k, 2 MFMA each).
// Per k: 128 B W + 64 B x  -> xpack re-read traffic halved vs 16x16 shape.
// XCD swizzle: xcd = bid&7 owns a contiguous 32 MB W band.
// Scales (x ws2) preloaded to LDS; intra-block 4-wave reduce; atomicAdd.
// ---------------------------------------------------------------------------
__global__ __launch_bounds__(256, 8) void gemm_kernel(
    const float* __restrict__ W,
    const float* __restrict__ wscale,
    const float* __restrict__ ws2p,
    const unsigned short* __restrict__ xpack,
    float* __restrict__ out)
{
    __shared__ float shm[4096];          // 16 KB: scales [32][66] then reduce [4][1024]

    // ---- XCD-bijective swizzle (2048 = 8 XCDs x 256 blocks) ----
    const int bid   = blockIdx.x;
    const int xcd   = bid & 7;
    const int local = bid >> 3;                 // 0..255 within XCD
    const int ntile = xcd * 32 + (local >> 3);  // 0..255 (32 rows each)
    const int kb    = local & 7;                // 0..7

    const int wave = threadIdx.x >> 6;   // k sub-split within block
    const int lane = threadIdx.x & 63;
    const int lrow = lane & 31;          // W row (n) sub-index / x m-col
    const int half = lane >> 5;          // k-half 0..1
    const int n0 = ntile * 32;
    const float ws2 = ws2p[0];

    // ---- preload scales * ws2: rows n0..n0+31, kblks kb*64..+64 ----
    {
        int t = threadIdx.x;
        int row = t >> 3;                // 0..31
        int c0 = (t & 7) * 8;            // 0..56
        const float* s = wscale + (size_t)(n0 + row) * NBLK + kb * 64 + c0;
        #pragma unroll
        for (int j = 0; j < 8; ++j)
            shm[row * SCL_LD + c0 + j] = s[j] * ws2;
    }
    __syncthreads();

    const int kofs = kb * 1024 + wave * 256;          // this wave's k start
    const float* wcur = W + (size_t)(n0 + lrow) * K_DIM + kofs + half * 8;
    // x: superstep ss0 = kofs>>5; lane reads 16B at (ss*4 + t*2 + half)*256 + lrow*8
    const unsigned short* xcur = xpack + ((size_t)(kofs >> 5) * 4 + half) * 256 + lrow * 8;
    const float* sbase = shm + lrow * SCL_LD + (kofs >> 4) - (size_t)(n0 + 0) * 0 - kb * 64 + 0;
    // simplify: local kblk index = (kofs>>4) - kb*64 = wave*16
    const float* scur = shm + lrow * SCL_LD + wave * 16;

    f32x16 acc = {};

    // depth-2 software pipeline over supersteps (compiler inserts vmcnt waits)
    f32x4 a00 = *(const f32x4*)(wcur);        // MFMA0: k = half*8 + 0..3
    f32x4 a01 = *(const f32x4*)(wcur + 4);    //        k = half*8 + 4..7
    f32x4 a10 = *(const f32x4*)(wcur + 16);   // MFMA1
    f32x4 a11 = *(const f32x4*)(wcur + 20);
    s16x4 b00 = *(const s16x4*)(xcur);
    s16x4 b01 = *(const s16x4*)(xcur + 4);
    s16x4 b10 = *(const s16x4*)(xcur + 512);
    s16x4 b11 = *(const s16x4*)(xcur + 516);

    #pragma unroll
    for (int s = 0; s < SSTEPS; ++s) {
        f32x4 na00, na01, na10, na11; s16x4 nb00, nb01, nb10, nb11;
        if (s + 1 < SSTEPS) {             // static with full unroll
            na00 = *(const f32x4*)(wcur + 32);
            na01 = *(const f32x4*)(wcur + 36);
            na10 = *(const f32x4*)(wcur + 48);
            na11 = *(const f32x4*)(wcur + 52);
            nb00 = *(const s16x4*)(xcur + 1024);
            nb01 = *(const s16x4*)(xcur + 1028);
            nb10 = *(const s16x4*)(xcur + 1536);
            nb11 = *(const s16x4*)(xcur + 1540);
        }
        float sc0 = scur[2 * s];
        float sc1 = scur[2 * s + 1];
        typedef short s16x8 __attribute__((ext_vector_type(8)));
        s16x8 af, bf;
        #pragma unroll
        for (int j = 0; j < 4; ++j) {
            af[j]     = (short)f2bf(a00[j] * sc0);
            af[4 + j] = (short)f2bf(a01[j] * sc0);
            bf[j]     = b00[j];
            bf[4 + j] = b01[j];
        }
        acc = __builtin_amdgcn_mfma_f32_32x32x16_bf16(af, bf, acc, 0, 0, 0);
        #pragma unroll
        for (int j = 0; j < 4; ++j) {
            af[j]     = (short)f2bf(a10[j] * sc1);
            af[4 + j] = (short)f2bf(a11[j] * sc1);
            bf[j]     = b10[j];
            bf[4 + j] = b11[j];
        }
        acc = __builtin_amdgcn_mfma_f32_32x32x16_bf16(af, bf, acc, 0, 0, 0);
        a00 = na00; a01 = na01; a10 = na10; a11 = na11;
        b00 = nb00; b01 = nb01; b10 = nb10; b11 = nb11;
        wcur += 32;
        xcur += 1024;
    }

    // ---- intra-block reduce over the 4 k-split waves ----
    __syncthreads();                      // scale reads done; reuse shm
    float* red = shm;                     // [4][1024]
    #pragma unroll
    for (int r = 0; r < 16; ++r) {
        int row = (r & 3) + 8 * (r >> 2) + 4 * half;   // verified C/D map
        red[wave * 1024 + row * 32 + lrow] = acc[r];
    }
    __syncthreads();

    // 256 threads -> 1024 outputs: idx = n_sub*32 + m
    #pragma unroll
    for (int h = 0; h < 4; ++h) {
        int j = threadIdx.x + h * 256;
        float v = red[j] + red[1024 + j] + red[2048 + j] + red[3072 + j];
        int m = j & 31;
        int n = n0 + (j >> 5);
        atomicAdd(out + (size_t)m * N_DIM + n, v);
    }
}

extern "C" void kernel_launch(void* const* d_in, const int* in_sizes, int n_in,
                              void* d_out, int out_size, void* d_ws, size_t ws_size,
                              hipStream_t stream) {
    const float* x           = (const float*)d_in[0];
    const float* weight_fp4  = (const float*)d_in[1];
    const float* bias        = (const float*)d_in[2];
    const float* input_scale = (const float*)d_in[3];
    const float* wscale      = (const float*)d_in[4];
    const float* ws2         = (const float*)d_in[5];
    float* out = (float*)d_out;
    unsigned short* xpack = (unsigned short*)d_ws;   // 512 KB

    prep_kernel<<<320, 256, 0, stream>>>(x, input_scale, bias, xpack, out);
    gemm_kernel<<<2048, 256, 0, stream>>>(weight_fp4, wscale, ws2, xpack, out);
}

// Round 11
// 89.140 us; speedup vs baseline: 1.0480x; 1.0480x over previous
//
#include <hip/hip_runtime.h>

typedef float f32x4 __attribute__((ext_vector_type(4)));
typedef short s16x8 __attribute__((ext_vector_type(8)));

#define M_DIM 32
#define N_DIM 8192
#define K_DIM 8192
#define NBLK (K_DIM / 16)   // 512 fp4 blocks along K
#define SSTEPS 8            // 32-k steps per wave (256 k)
#define SCL_LD 65           // padded LDS stride for scales

// float -> bf16 bits, round-to-nearest-even (data has no NaNs)
__device__ inline unsigned short f2bf(float f) {
    unsigned int u = __float_as_uint(f);
    u = (u + 0x7FFFu + ((u >> 16) & 1u)) >> 16;
    return (unsigned short)u;
}

// Nearest FP4 (e2m1); ties at the boundary go DOWN (searchsorted side='left').
__device__ inline float round_fp4(float x) {
    float a = fabsf(x);
    float g;
    if (a > 2.5f)        g = (a > 5.0f) ? 6.0f : ((a > 3.5f) ? 4.0f : 3.0f);
    else if (a > 1.25f)  g = (a > 1.75f) ? 2.0f : 1.5f;
    else                 g = (a > 0.75f) ? 1.0f : ((a > 0.25f) ? 0.5f : 0.0f);
    return copysignf(g, x);
}

// Saturating RNE cast to float8_e4m3fn and back (v >= 0 here).
__device__ inline float cast_e4m3(float v) {
    v = fminf(v, 448.0f);
    if (v < 0.015625f) {                       // subnormal range, step 2^-9
        return rintf(v * 512.0f) * (1.0f / 512.0f);
    }
    int e; float m = frexpf(v, &e);            // m in [0.5, 1)
    return ldexpf(rintf(m * 16.0f) * 0.0625f, e);
}

// ---------------------------------------------------------------------------
// Fused prep (r7 exact): blocks 0..63  -> NVFP4 fake-quant of x into xpack
//                        blocks 64..319 -> out[m][n] = bias[n]
// xpack layout (r7, verified): base = kstep*1024 + t*512; index lane*8+j where
//   lane = g*16 + (m&15), t = m>>4, g = k-group; holds x_dq[m][kstep*32+g*8+j]
// ---------------------------------------------------------------------------
__global__ void prep_kernel(const float* __restrict__ x,
                            const float* __restrict__ input_scale,
                            const float* __restrict__ bias,
                            unsigned short* __restrict__ xpack,
                            float* __restrict__ out) {
    if (blockIdx.x >= 64) {
        int i = (blockIdx.x - 64) * blockDim.x + threadIdx.x;  // 65536 thr * 4 f
        f32x4 b = *(const f32x4*)(bias + ((i * 4) & (N_DIM - 1)));
        *(f32x4*)(out + (size_t)i * 4) = b;
        return;
    }
    int tid = blockIdx.x * blockDim.x + threadIdx.x;   // 16384 threads
    int m = tid >> 9;          // row 0..31
    int b = tid & 511;         // 16-block along K
    const float is = input_scale[0];

    const float* xp = x + (size_t)m * K_DIM + b * 16;
    f32x4 l0 = *(const f32x4*)(xp);
    f32x4 l1 = *(const f32x4*)(xp + 4);
    f32x4 l2 = *(const f32x4*)(xp + 8);
    f32x4 l3 = *(const f32x4*)(xp + 12);
    float v[16];
    #pragma unroll
    for (int i = 0; i < 4; ++i) { v[i]=l0[i]; v[4+i]=l1[i]; v[8+i]=l2[i]; v[12+i]=l3[i]; }

    float amax = 0.f;
    #pragma unroll
    for (int i = 0; i < 16; ++i) amax = fmaxf(amax, fabsf(v[i]));

    float sf = cast_e4m3(amax / 6.0f / is);
    float scale = sf * is;

    int kstep = b >> 1;
    int t = m >> 4;
    int mrow = m & 15;
    unsigned short* base = xpack + (size_t)kstep * 1024 + t * 512;
    #pragma unroll
    for (int i = 0; i < 16; ++i) {
        float q = 0.f;
        if (scale > 0.f) q = round_fp4(v[i] / scale) * scale;
        int g = ((b & 1) << 1) + (i >> 3);   // k-group 0..3 within kstep
        int lane = g * 16 + mrow;
        int j = i & 7;
        base[lane * 8 + j] = f2bf(q);
    }
}

// ---------------------------------------------------------------------------
// Phase 2: streaming split-K GEMM, 16x16x32, 32 n-rows per wave sharing one
// B-fragment pair -> xpack re-read traffic halved vs r7 (256 -> 128 MB).
// Grid 2048 x 256 thr (4 waves) -> 8 blocks/CU, 32 waves/CU.
// Block: 32 rows x 1024 k; wave: 32 rows x 256 k (8 steps, 4 MFMA each).
// No manual prefetch regs (fits 64 VGPR); TLP + compiler hoisting hide latency.
// XCD swizzle: xcd = bid&7 owns a contiguous 32 MB W band.
// ---------------------------------------------------------------------------
__global__ __launch_bounds__(256, 8) void gemm_kernel(
    const float* __restrict__ W,
    const float* __restrict__ wscale,
    const float* __restrict__ ws2p,
    const unsigned short* __restrict__ xpack,
    float* __restrict__ out)
{
    __shared__ float shm[4096];          // 16 KB: scales [32][65], then red [4][1024]

    // ---- XCD-bijective swizzle (2048 = 8 XCDs x 256 blocks) ----
    const int bid   = blockIdx.x;
    const int xcd   = bid & 7;
    const int local = bid >> 3;                 // 0..255 within XCD
    const int ntile = xcd * 32 + (local >> 3);  // 0..255 (32 rows each)
    const int kb    = local & 7;                // 0..7

    const int wave = threadIdx.x >> 6;   // k sub-split within block
    const int lane = threadIdx.x & 63;
    const int lrow = lane & 15;          // row sub-index (A) / m col (B)
    const int lgrp = lane >> 4;          // k-group 0..3
    const int n0 = ntile * 32;
    const float ws2 = ws2p[0];

    // ---- preload scales * ws2: rows n0..n0+31, kblks kb*64..+64 ----
    {
        int t = threadIdx.x;
        int row = t >> 3;                // 0..31
        int c0 = (t & 7) * 8;            // 0..56
        const float* s = wscale + (size_t)(n0 + row) * NBLK + kb * 64 + c0;
        #pragma unroll
        for (int j = 0; j < 8; ++j)
            shm[row * SCL_LD + c0 + j] = s[j] * ws2;
    }
    __syncthreads();

    const int kofs = kb * 1024 + wave * 256;          // this wave's k start
    const float* wcur0 = W + (size_t)(n0 + lrow) * K_DIM + kofs + lgrp * 8;
    const float* wcur1 = wcur0 + (size_t)16 * K_DIM;
    const unsigned short* xcur = xpack + (size_t)(kofs >> 5) * 1024 + lane * 8;
    // scale col index within block: wave*16 + 2s + (lgrp>>1)
    const float* scur0 = shm + lrow * SCL_LD + wave * 16 + (lgrp >> 1);
    const float* scur1 = scur0 + 16 * SCL_LD;

    f32x4 acc00 = {0,0,0,0}, acc01 = {0,0,0,0};
    f32x4 acc10 = {0,0,0,0}, acc11 = {0,0,0,0};

    #pragma unroll
    for (int s = 0; s < SSTEPS; ++s) {
        f32x4 a00 = *(const f32x4*)(wcur0 + s * 32);
        f32x4 a01 = *(const f32x4*)(wcur0 + s * 32 + 4);
        f32x4 a10 = *(const f32x4*)(wcur1 + s * 32);
        f32x4 a11 = *(const f32x4*)(wcur1 + s * 32 + 4);
        s16x8 b0 = *(const s16x8*)(xcur + (size_t)s * 1024);
        s16x8 b1 = *(const s16x8*)(xcur + (size_t)s * 1024 + 512);
        float sc0 = scur0[2 * s];
        float sc1 = scur1[2 * s];
        s16x8 af0, af1;
        #pragma unroll
        for (int j = 0; j < 4; ++j) {
            af0[j]     = (short)f2bf(a00[j] * sc0);
            af0[4 + j] = (short)f2bf(a01[j] * sc0);
            af1[j]     = (short)f2bf(a10[j] * sc1);
            af1[4 + j] = (short)f2bf(a11[j] * sc1);
        }
        acc00 = __builtin_amdgcn_mfma_f32_16x16x32_bf16(af0, b0, acc00, 0, 0, 0);
        acc01 = __builtin_amdgcn_mfma_f32_16x16x32_bf16(af0, b1, acc01, 0, 0, 0);
        acc10 = __builtin_amdgcn_mfma_f32_16x16x32_bf16(af1, b0, acc10, 0, 0, 0);
        acc11 = __builtin_amdgcn_mfma_f32_16x16x32_bf16(af1, b1, acc11, 0, 0, 0);
    }

    // ---- intra-block reduce over the 4 k-split waves ----
    __syncthreads();                      // scale reads done; reuse shm
    float* red = shm;                     // [4][1024], idx = n_local*32 + m
    // C/D map (verified): col = lane&15 (m sub), row = lgrp*4 + r (n sub)
    #pragma unroll
    for (int r = 0; r < 4; ++r) {
        int nl = lgrp * 4 + r;
        red[wave * 1024 + nl * 32 + lrow]              = acc00[r];
        red[wave * 1024 + nl * 32 + 16 + lrow]         = acc01[r];
        red[wave * 1024 + (16 + nl) * 32 + lrow]       = acc10[r];
        red[wave * 1024 + (16 + nl) * 32 + 16 + lrow]  = acc11[r];
    }
    __syncthreads();

    // 256 threads -> 1024 outputs: j = n_local*32 + m
    #pragma unroll
    for (int h = 0; h < 4; ++h) {
        int j = threadIdx.x + h * 256;
        float v = red[j] + red[1024 + j] + red[2048 + j] + red[3072 + j];
        int m = j & 31;
        int n = n0 + (j >> 5);
        atomicAdd(out + (size_t)m * N_DIM + n, v);
    }
}

extern "C" void kernel_launch(void* const* d_in, const int* in_sizes, int n_in,
                              void* d_out, int out_size, void* d_ws, size_t ws_size,
                              hipStream_t stream) {
    const float* x           = (const float*)d_in[0];
    const float* weight_fp4  = (const float*)d_in[1];
    const float* bias        = (const float*)d_in[2];
    const float* input_scale = (const float*)d_in[3];
    const float* wscale      = (const float*)d_in[4];
    const float* ws2         = (const float*)d_in[5];
    float* out = (float*)d_out;
    unsigned short* xpack = (unsigned short*)d_ws;   // 512 KB

    prep_kernel<<<320, 256, 0, stream>>>(x, input_scale, bias, xpack, out);
    gemm_kernel<<<2048, 256, 0, stream>>>(weight_fp4, wscale, ws2, xpack, out);
}